// Round 8
// baseline (990.749 us; speedup 1.0000x reference)
//
#include <hip/hip_runtime.h>

#define B_ 4
#define S_ 4096
#define IN_ 1024
#define H_ 16
#define D_ 64
#define OUT_ 1024
#define HD_ 1024   // H*D
#define M_ 16384   // B*S

typedef __bf16 bf16x8 __attribute__((ext_vector_type(8)));
typedef __bf16 bf16x2 __attribute__((ext_vector_type(2)));
typedef float floatx4 __attribute__((ext_vector_type(4)));
typedef int int32x4 __attribute__((ext_vector_type(4)));

#define TWO_LOG2E 2.885390081777927f   // 2*log2(e)

static __device__ __forceinline__ unsigned int f2bf(float f) {
    unsigned int u = __builtin_bit_cast(unsigned int, f);
    u += 0x7fffu + ((u >> 16) & 1u);   // round-to-nearest-even
    return u >> 16;
}

// ---------------- cast fp32 -> bf16, vectorized x4 ----------------
__global__ void cast_f32_bf16(const float* __restrict__ src,
                              unsigned short* __restrict__ dst, int n4) {
    int i = blockIdx.x * blockDim.x + threadIdx.x;
    if (i < n4) {
        float4 v = ((const float4*)src)[i];
        ushort4 o;
        o.x = (unsigned short)f2bf(v.x); o.y = (unsigned short)f2bf(v.y);
        o.z = (unsigned short)f2bf(v.z); o.w = (unsigned short)f2bf(v.w);
        ((ushort4*)dst)[i] = o;
    }
}

// ---------------- bf16 MFMA GEMM: C[M,N] = A[M,K] * B[N,K]^T ----------------
// global_load_lds width=16 into LINEAR [128][32] LDS (m97 structure).
__global__ __launch_bounds__(256) void gemm_bt(
    const unsigned short* __restrict__ A,   // [M,K] bf16
    const unsigned short* __restrict__ Bm,  // [N,K] bf16
    float* __restrict__ C, int M, int N, int K) {
    __shared__ unsigned short As[128 * 32];
    __shared__ unsigned short Bs[128 * 32];
    const int t = threadIdx.x;
    const int lane = t & 63;
    const int wave = t >> 6;
    const int wm = wave >> 1, wn = wave & 1;
    const int m0 = blockIdx.y * 128;
    const int n0 = blockIdx.x * 128;
    const int l16 = lane & 15;
    const int quad = lane >> 4;
    const int r16 = lane >> 2;      // row within 16-row chunk
    const int kc = lane & 3;        // 8-ushort k-slot within row

    floatx4 acc[4][4];
#pragma unroll
    for (int i = 0; i < 4; i++)
#pragma unroll
        for (int j = 0; j < 4; j++) acc[i][j] = (floatx4){0.f, 0.f, 0.f, 0.f};

    for (int k0 = 0; k0 < K; k0 += 32) {
#pragma unroll
        for (int it = 0; it < 2; it++) {
            int chunk = wave * 2 + it;              // 0..7
            int row = chunk * 16 + r16;
            const unsigned short* ga = A + (size_t)(m0 + row) * K + k0 + kc * 8;
            __builtin_amdgcn_global_load_lds(
                (const __attribute__((address_space(1))) void*)ga,
                (__attribute__((address_space(3))) void*)(As + chunk * 512),
                16, 0, 0);
            const unsigned short* gb = Bm + (size_t)(n0 + row) * K + k0 + kc * 8;
            __builtin_amdgcn_global_load_lds(
                (const __attribute__((address_space(1))) void*)gb,
                (__attribute__((address_space(3))) void*)(Bs + chunk * 512),
                16, 0, 0);
        }
        __syncthreads();
        bf16x8 af[4], bfr[4];
#pragma unroll
        for (int i = 0; i < 4; i++)
            af[i] = *(const bf16x8*)(As + (wm * 64 + i * 16 + l16) * 32 + quad * 8);
#pragma unroll
        for (int j = 0; j < 4; j++)
            bfr[j] = *(const bf16x8*)(Bs + (wn * 64 + j * 16 + l16) * 32 + quad * 8);
#pragma unroll
        for (int i = 0; i < 4; i++)
#pragma unroll
            for (int j = 0; j < 4; j++)
                acc[i][j] = __builtin_amdgcn_mfma_f32_16x16x32_bf16(
                    af[i], bfr[j], acc[i][j], 0, 0, 0);
        __syncthreads();
    }
#pragma unroll
    for (int i = 0; i < 4; i++)
#pragma unroll
        for (int j = 0; j < 4; j++)
#pragma unroll
            for (int r = 0; r < 4; r++) {
                int row = m0 + wm * 64 + i * 16 + quad * 4 + r;
                int col = n0 + wn * 64 + j * 16 + l16;
                C[(size_t)row * N + col] = acc[i][j][r];
            }
}

// ---------------- sequential RNN scan (v12: LDS-batched y stores) -----------
// 64 blocks (one (b,h) chain), ONE wave, 1 wave/CU. v11 measured 415
// cyc/step; issue = 46 VALU + 32 MFMA cyc, stall = 337. Hypothesis under
// test: the per-step global_store_short shares vmcnt with the bx prefetch
// loads, serializing store completion into the chain (vmcnt waits cover
// older stores). Fix: per-step output goes to a 2KB LDS buffer
// (ds_write_b16, lgkm counter, no wait on path); every 16 steps one flush:
// lgkmcnt wait + 2x ds_read_b128 + 2x coalesced global_store_dwordx4.
// Steady-state vmcnt then tracks only the 8 x-loads per 8 steps.
__global__ __launch_bounds__(64, 1) void rnn_scan(
    const float* __restrict__ xp,      // [B,S,H,D] fp32 (GEMM1 output)
    const float* __restrict__ w_h,     // [H,D,D]
    const float* __restrict__ bias,    // [H,D]
    const float* __restrict__ h0,      // [B,H,D]
    unsigned short* __restrict__ y) {  // [B,S,H,D] bf16
    __shared__ unsigned short ylds[16 * 64];   // [t-slot][element]
    const int bh = blockIdx.x;
    const int b = bh >> 4;
    const int h = bh & 15;
    const int e = threadIdx.x;
    const int c = e & 15;           // fragment column index
    const int q = e >> 4;           // 16-lane group (row)

    // ---- static W^T B-fragments under pi (group q supplies h[16q..16q+15]),
    // scaled by 2*log2e.
    auto loadB = [&](int nt, int koff) -> bf16x8 {
        const float* wr = w_h + ((size_t)(h * 64 + nt * 16 + c)) * 64 + q * 16 + koff;
        float4 v0 = ((const float4*)wr)[0];
        float4 v1 = ((const float4*)wr)[1];
        int32x4 bi;
        bi[0] = (int)(f2bf(v0.x * TWO_LOG2E) | (f2bf(v0.y * TWO_LOG2E) << 16));
        bi[1] = (int)(f2bf(v0.z * TWO_LOG2E) | (f2bf(v0.w * TWO_LOG2E) << 16));
        bi[2] = (int)(f2bf(v1.x * TWO_LOG2E) | (f2bf(v1.y * TWO_LOG2E) << 16));
        bi[3] = (int)(f2bf(v1.z * TWO_LOG2E) | (f2bf(v1.w * TWO_LOG2E) << 16));
        return __builtin_bit_cast(bf16x8, bi);
    };
    const bf16x8 BfA0 = loadB(0, 0), BfB0 = loadB(0, 8);
    const bf16x8 BfA1 = loadB(1, 0), BfB1 = loadB(1, 8);
    const bf16x8 BfA2 = loadB(2, 0), BfB2 = loadB(2, 8);
    const bf16x8 BfA3 = loadB(3, 0), BfB3 = loadB(3, 8);

    const bool q1 = (q & 1) != 0;
    const bool q2 = (q & 2) != 0;

    const float be = bias[h * 64 + e];
    float hn = h0[(b * 16 + h) * 64 + e];   // f32 state, 1/lane

    const float* xb = xp + ((size_t)(b * S_) * 16 + h) * 64 + e;  // + t*1024
    unsigned short* ybase = y + ((size_t)(b * S_) * 16 + h) * 64;  // no +e

    // flush lane mapping: lane e stores t-slot (e>>3), 16B chunk (e&7)*8
    const int fr = e >> 3;          // 0..7
    const int fc = (e & 7) * 8;     // ushort offset within row

    // prefetched 2L*(bias+x) (off the dependent path)
    float bxA[8], bxB[8];
#pragma unroll
    for (int i2 = 0; i2 < 8; i2++)
        bxA[i2] = (be + xb[(size_t)i2 * 1024]) * TWO_LOG2E;
#pragma unroll
    for (int i2 = 0; i2 < 8; i2++)
        bxB[i2] = (be + xb[(size_t)(8 + i2) * 1024]) * TWO_LOG2E;

    auto step = [&](int u, float bx) {   // u = t within 16-step block
        // neighbor's f32 h via quad_perm [1,1,3,3] (even lane 2d gets h[2d+1])
        float hs = __builtin_bit_cast(float, __builtin_amdgcn_update_dpp(
            0, __builtin_bit_cast(int, hn), 0xF5, 0xF, 0xF, true));
        unsigned int pk;
        asm("v_cvt_pk_bf16_f32 %0, %1, %2" : "=v"(pk) : "v"(hn), "v"(hs));
        int32x4 a0i, a1i;
        a0i[0] = __builtin_amdgcn_update_dpp(0, (int)pk, 0x150 + 0,  0xF, 0xF, true);
        a0i[1] = __builtin_amdgcn_update_dpp(0, (int)pk, 0x150 + 2,  0xF, 0xF, true);
        a0i[2] = __builtin_amdgcn_update_dpp(0, (int)pk, 0x150 + 4,  0xF, 0xF, true);
        a0i[3] = __builtin_amdgcn_update_dpp(0, (int)pk, 0x150 + 6,  0xF, 0xF, true);
        a1i[0] = __builtin_amdgcn_update_dpp(0, (int)pk, 0x150 + 8,  0xF, 0xF, true);
        a1i[1] = __builtin_amdgcn_update_dpp(0, (int)pk, 0x150 + 10, 0xF, 0xF, true);
        a1i[2] = __builtin_amdgcn_update_dpp(0, (int)pk, 0x150 + 12, 0xF, 0xF, true);
        a1i[3] = __builtin_amdgcn_update_dpp(0, (int)pk, 0x150 + 14, 0xF, 0xF, true);
        bf16x8 A0 = __builtin_bit_cast(bf16x8, a0i);   // h[16q + 0..7]
        bf16x8 A1 = __builtin_bit_cast(bf16x8, a1i);   // h[16q + 8..15]
        const floatx4 z4 = (floatx4){0.f, 0.f, 0.f, 0.f};
        const floatx4 cb = (floatx4){bx, 0.f, 0.f, 0.f};  // bx rides in C reg0
        floatx4 acA0 = __builtin_amdgcn_mfma_f32_16x16x32_bf16(A0, BfA0, cb, 0, 0, 0);
        floatx4 acB0 = __builtin_amdgcn_mfma_f32_16x16x32_bf16(A1, BfB0, z4, 0, 0, 0);
        floatx4 acA1 = __builtin_amdgcn_mfma_f32_16x16x32_bf16(A0, BfA1, cb, 0, 0, 0);
        floatx4 acB1 = __builtin_amdgcn_mfma_f32_16x16x32_bf16(A1, BfB1, z4, 0, 0, 0);
        floatx4 acA2 = __builtin_amdgcn_mfma_f32_16x16x32_bf16(A0, BfA2, cb, 0, 0, 0);
        floatx4 acB2 = __builtin_amdgcn_mfma_f32_16x16x32_bf16(A1, BfB2, z4, 0, 0, 0);
        floatx4 acA3 = __builtin_amdgcn_mfma_f32_16x16x32_bf16(A0, BfA3, cb, 0, 0, 0);
        floatx4 acB3 = __builtin_amdgcn_mfma_f32_16x16x32_bf16(A1, BfB3, z4, 0, 0, 0);
        float yA01 = q1 ? acA1[0] : acA0[0];
        float yA23 = q1 ? acA3[0] : acA2[0];
        float yA   = q2 ? yA23 : yA01;
        float yB01 = q1 ? acB1[0] : acB0[0];
        float yB23 = q1 ? acB3[0] : acB2[0];
        float yB   = q2 ? yB23 : yB01;
        float pre = yA + yB;                       // = 2*log2e * preact
        float em = __builtin_amdgcn_exp2f(pre);
        float r  = __builtin_amdgcn_rcpf(em + 1.0f);
        hn = fmaf(-2.0f, r, 1.0f);
        // output -> LDS (lgkm counter; no vmem store on the serial path)
        ylds[u * 64 + e] = (unsigned short)f2bf(hn);
    };

    for (int t0 = 0; t0 < S_; t0 += 16) {
#pragma unroll
        for (int u = 0; u < 8; u++) step(u, bxA[u]);
        if (t0 + 16 < S_) {
#pragma unroll
            for (int i2 = 0; i2 < 8; i2++)
                bxA[i2] = (be + xb[(size_t)(t0 + 16 + i2) * 1024]) * TWO_LOG2E;
        }
#pragma unroll
        for (int u = 0; u < 8; u++) step(8 + u, bxB[u]);
        if (t0 + 24 < S_) {
#pragma unroll
            for (int i2 = 0; i2 < 8; i2++)
                bxB[i2] = (be + xb[(size_t)(t0 + 24 + i2) * 1024]) * TWO_LOG2E;
        }
        // flush 16 t-slots: lane e handles slot fr (v0) and 8+fr (v1)
        uint4 v0 = *(const uint4*)(ylds + fr * 64 + fc);
        uint4 v1 = *(const uint4*)(ylds + (8 + fr) * 64 + fc);
        *(uint4*)(ybase + (size_t)(t0 + fr) * 1024 + fc) = v0;
        *(uint4*)(ybase + (size_t)(t0 + 8 + fr) * 1024 + fc) = v1;
    }
}

extern "C" void kernel_launch(void* const* d_in, const int* in_sizes, int n_in,
                              void* d_out, int out_size, void* d_ws, size_t ws_size,
                              hipStream_t stream) {
    const float* x     = (const float*)d_in[0];  // [B,S,IN]
    const float* h0    = (const float*)d_in[1];  // [B,H,D]
    const float* w_in  = (const float*)d_in[2];  // [HD,IN]
    const float* w_h   = (const float*)d_in[3];  // [H,D,D]
    const float* bias  = (const float*)d_in[4];  // [H,D]
    const float* w_out = (const float*)d_in[5];  // [OUT,HD]
    float* out = (float*)d_out;                  // [B,S,OUT] fp32; doubles as xp scratch

    char* ws = (char*)d_ws;
    unsigned short* x_bf    = (unsigned short*)(ws);                       // 33.5 MB
    unsigned short* win_bf  = (unsigned short*)(ws + (size_t)33554432);    // 2 MB
    unsigned short* wout_bf = (unsigned short*)(ws + (size_t)35651584);    // 2 MB
    unsigned short* y_bf    = (unsigned short*)(ws + (size_t)37748736);    // 33.5 MB

    {
        int n4 = (M_ * IN_) / 4;
        cast_f32_bf16<<<(n4 + 255) / 256, 256, 0, stream>>>(x, x_bf, n4);
        int w4 = (HD_ * IN_) / 4;
        cast_f32_bf16<<<(w4 + 255) / 256, 256, 0, stream>>>(w_in, win_bf, w4);
        cast_f32_bf16<<<(w4 + 255) / 256, 256, 0, stream>>>(w_out, wout_bf, w4);
    }
    // GEMM1: xp = x @ w_in^T  -> stored in d_out as scratch
    dim3 g1(HD_ / 128, M_ / 128);
    gemm_bt<<<g1, 256, 0, stream>>>(x_bf, win_bf, out, M_, HD_, IN_);
    // sequential scan: reads xp (d_out), writes y_bf (64 chains, 1 wave/CU)
    rnn_scan<<<64, 64, 0, stream>>>(out, w_h, bias, h0, y_bf);
    // GEMM2: out = y @ w_out^T  -> overwrites d_out
    dim3 g2(OUT_ / 128, M_ / 128);
    gemm_bt<<<g2, 256, 0, stream>>>(y_bf, wout_bf, out, M_, OUT_, HD_);
}